// Round 11
// baseline (114.783 us; speedup 1.0000x reference)
//
#include <hip/hip_runtime.h>
#include <hip/hip_bf16.h>

typedef unsigned short u16;
typedef __attribute__((ext_vector_type(8))) short short8;
typedef __attribute__((ext_vector_type(4))) float f32x4;

#define HID 128
#define WNUMEL 3072
#define OUTD 144

// ---------- fused pre-pass: W2 swizzle | MLP | sh + linked-list build ----------
__global__ void k_pre(const float* __restrict__ W2, __hip_bfloat16* __restrict__ W2s,
                      const float* __restrict__ es, const float* __restrict__ W1,
                      const float* __restrict__ b1, __hip_bfloat16* __restrict__ h2s,
                      const float* __restrict__ ev, const int* __restrict__ dst,
                      float* __restrict__ shb, int* __restrict__ head,
                      int* __restrict__ nxt, int E, int NW, int NM) {
  __shared__ float esl[8][32];
  const int b = blockIdx.x, tid = threadIdx.x;
  if (b < NW) {
    // W2 swizzle, coalesced READ side: f = k*3072+n, scatter-write bf16
    int f = b * 256 + tid;                            // < 128*3072
    int k = f / WNUMEL, n = f - k * WNUMEL;
    int s = k >> 5, h = (k >> 3) & 3, i = k & 7;
    int tt = n >> 4, c = n & 15;
    W2s[((size_t)(tt * 4 + s) * 64 + (c + 16 * h)) * 8 + i] = __float2bfloat16(W2[f]);
  } else if (b < NW + NM) {
    int e0 = (b - NW) * 8;
    {
      int e = e0 + (tid >> 5);
      esl[tid >> 5][tid & 31] = (e < E) ? es[e * 32 + (tid & 31)] : 0.f;
    }
    __syncthreads();
    int h = tid & 127;
    float bh = b1[h];
#pragma unroll
    for (int r = 0; r < 4; ++r) {
      int eloc = (tid >> 7) + r * 2;
      int e = e0 + eloc;
      if (e < E) {
        float acc = bh;
#pragma unroll
        for (int i = 0; i < 32; ++i) acc = fmaf(esl[eloc][i], W1[i * HID + h], acc);
        float sg = 1.f / (1.f + expf(-acc));
        float z = acc * sg * 0.125f;                  // fold 1/sqrt(64)
        int s = h >> 5, hh = (h >> 3) & 3, i = h & 7;
        int lane = (e & 15) + 16 * hh, eblk = e >> 4;
        h2s[((size_t)(eblk * 4 + s) * 64 + lane) * 8 + i] = __float2bfloat16(z);
      }
    }
  } else {
    int e = (b - NW - NM) * 256 + tid;
    if (e >= E) return;
    float vx = ev[e * 3 + 0], vy = ev[e * 3 + 1], vz = ev[e * 3 + 2];
    float nrm = fmaxf(sqrtf(vx * vx + vy * vy + vz * vz), 1e-9f);
    float x = vx / nrm, y = vy / nrm, z = vz / nrm;
    const float SQ3 = 1.7320508075688772f, SQ5 = 2.2360679774997896f,
                SQ15 = 3.872983346207417f;
    float* sp = shb + (size_t)e * 9;
    sp[0] = 1.f;
    sp[1] = SQ3 * x; sp[2] = SQ3 * y; sp[3] = SQ3 * z;
    sp[4] = SQ15 * x * y; sp[5] = SQ15 * y * z;
    sp[6] = 0.5f * SQ5 * (3.f * z * z - 1.f);
    sp[7] = SQ15 * x * z;
    sp[8] = 0.5f * SQ15 * (x * x - y * y);
    nxt[e] = atomicExch(&head[dst[e]], e);           // per-dst linked list
  }
}

// ---------- fused GEMM + x-contraction -> feat[E][48] ----------
// grid = (E/64, 3). Wave owns 16 N-tiles of l-path blockIdx.y, processed as
// 4 quads (T=4). Per quad: acc[4][4] (64 VGPRs) held across the K loop; each
// A-fragment load feeds 4 MFMAs (A traffic amortized 4x vs R6's remat).
// launch_bounds(256,2): RA cap 256 so acc does NOT spill (R8's failure was
// this structure under the (256,4)=128-VGPR cap -> scratch). A read directly
// from global (L1-hot, fragment-linear); B streamed from L2.
__global__ __launch_bounds__(256, 2) void k_gemm(
    const u16* __restrict__ h2s, const u16* __restrict__ W2s,
    const float* __restrict__ hsrc, const int* __restrict__ srci,
    const float* __restrict__ b2, float* __restrict__ feat_out, int E) {
  __shared__ float lds[4160];          // xT[64u][64e] (16KB), then fl[4][1040]
  float* xT = lds;
  float* fl = lds;
  const int tid = threadIdx.x, lane = tid & 63, wave = tid >> 6;
  const int blk = blockIdx.x, l3 = blockIdx.y;
  const int c = lane & 15, g = lane >> 4;

  // stage x transposed (wave w stages u-rows [w*16, w*16+16))
  {
    int e = lane, u0 = wave * 16;
    int eg = min(blk * 64 + e, E - 1);
    const float* xr = hsrc + (size_t)srci[eg] * 64 + u0;
#pragma unroll
    for (int k = 0; k < 16; ++k) xT[(u0 + k) * 64 + e] = xr[k];
  }
  __syncthreads();

  float feat[4][4] = {};               // [mt][j], this l-path, this wave's u-range
  const int T0 = l3 * 64 + wave * 16;
  const u16* Bg = W2s + (size_t)T0 * 2048;
  const u16* Ag = h2s + (size_t)blk * 8192;
  const float* b2g = b2 + T0 * 16 + c;

#pragma unroll
  for (int kq = 0; kq < 4; ++kq) {     // 4 quads of N-tiles
    float b2v[4];
#pragma unroll
    for (int t = 0; t < 4; ++t) b2v[t] = 0.125f * b2g[(kq * 4 + t) * 16];
    f32x4 acc[4][4];                   // [t][mt] — 64 regs, short live range (one quad)
#pragma unroll
    for (int t = 0; t < 4; ++t)
#pragma unroll
      for (int mt = 0; mt < 4; ++mt)
        acc[t][mt] = (f32x4){b2v[t], b2v[t], b2v[t], b2v[t]};
#pragma unroll
    for (int s = 0; s < 4; ++s) {
      short8 bfs[4];
#pragma unroll
      for (int t = 0; t < 4; ++t)
        bfs[t] = *(const short8*)(Bg + ((size_t)((kq * 4 + t) * 4 + s) * 64 + lane) * 8);
#pragma unroll
      for (int mt = 0; mt < 4; ++mt) {
        short8 a = *(const short8*)(Ag + ((mt * 4 + s) * 64 + lane) * 8);
#pragma unroll
        for (int t = 0; t < 4; ++t)
          acc[t][mt] = __builtin_amdgcn_mfma_f32_16x16x32_bf16(a, bfs[t], acc[t][mt], 0, 0, 0);
      }
    }
    // x-contraction for the 4 finished tiles (ends acc's live range)
#pragma unroll
    for (int t = 0; t < 4; ++t) {
      const float* xb = &xT[(wave * 16 + kq * 4 + t) * 64 + g * 4];
#pragma unroll
      for (int mt = 0; mt < 4; ++mt) {
        const float4 xv = *(const float4*)(xb + mt * 16);
#pragma unroll
        for (int j = 0; j < 4; ++j)
          feat[mt][j] = fmaf((&xv.x)[j], acc[t][mt][j], feat[mt][j]);
      }
    }
  }

  // cross-wave feat reduction in LDS (reuses xT space — barrier first)
  __syncthreads();
#pragma unroll
  for (int mt = 0; mt < 4; ++mt)
#pragma unroll
    for (int j = 0; j < 4; ++j)
      fl[wave * 1040 + (mt * 16 + g * 4 + j) * 16 + c] = feat[mt][j];
  __syncthreads();

  // epilogue: sum the 4 wave-partials, store compact feat slice for this l3
#pragma unroll
  for (int r = 0; r < 4; ++r) {
    int p = r * 256 + tid;             // 1024 = 64 edges x 16 v
    int eloc = p >> 4, v = p & 15;
    float f = fl[p] + fl[1040 + p] + fl[2080 + p] + fl[3120 + p];
    int e = blk * 64 + eloc;
    if (e < E) feat_out[(size_t)e * 48 + l3 * 16 + v] = f;
  }
}

// ---------- gather: one wave per dst; walk linked list; apply sh; mean ----------
__global__ void k_gather(const float* __restrict__ feat, const float* __restrict__ shb,
                         const int* __restrict__ head, const int* __restrict__ nxt,
                         float* __restrict__ out, int n_dst) {
  int d = blockIdx.x * 4 + (threadIdx.x >> 6);
  int lane = threadIdx.x & 63;
  if (d >= n_dst) return;
  int fi[4], si[4];
#pragma unroll
  for (int r = 0; r < 4; ++r) {
    int o = lane * 4 + r;
    if (o < 16)      { fi[r] = o;                 si[r] = 0; }        // sh[0] == 1
    else if (o < 64) { int id = o - 16; fi[r] = 16 + id / 3; si[r] = 1 + id % 3; }
    else             { int id = o - 64; fi[r] = 32 + id / 5; si[r] = 4 + id % 5; }
  }
  int e = head[d];                     // same addr across lanes -> broadcast load
  float4 acc = {0.f, 0.f, 0.f, 0.f};
  int deg = 0;
  while (e >= 0) {
    int en = nxt[e];                   // issue next-pointer first (chase overlap)
    if (lane < 36) {
      const float* fp = feat + (size_t)e * 48;
      const float* sp = shb + (size_t)e * 9;
#pragma unroll
      for (int r = 0; r < 4; ++r)
        (&acc.x)[r] = fmaf(fp[fi[r]], sp[si[r]], (&acc.x)[r]);
    }
    ++deg;
    e = en;
  }
  if (lane < 36) {
    float inv = 1.f / (float)max(deg, 1);
    acc.x *= inv; acc.y *= inv; acc.z *= inv; acc.w *= inv;
    *(float4*)&out[(size_t)d * OUTD + lane * 4] = acc;
  }
}

extern "C" void kernel_launch(void* const* d_in, const int* in_sizes, int n_in,
                              void* d_out, int out_size, void* d_ws, size_t ws_size,
                              hipStream_t stream) {
  const float* h_src        = (const float*)d_in[0];
  const float* edge_vec     = (const float*)d_in[1];
  const float* edge_scalars = (const float*)d_in[2];
  const float* W1           = (const float*)d_in[3];
  const float* b1           = (const float*)d_in[4];
  const float* W2           = (const float*)d_in[5];
  const float* b2           = (const float*)d_in[6];
  const int*   src_idx      = (const int*)d_in[7];
  const int*   dst_idx      = (const int*)d_in[8];

  const int E = in_sizes[1] / 3;
  const int n_dst = out_size / OUTD;
  const int nblk64 = (E + 63) / 64;
  const size_t E_pad = (size_t)nblk64 * 64;

  char* w = (char*)d_ws;
  auto al = [](size_t x) { return (x + 255) & ~(size_t)255; };
  size_t o = 0;
  float* shb = (float*)(w + o);                   o += al(E_pad * 9 * 4);
  __hip_bfloat16* h2s = (__hip_bfloat16*)(w + o); o += al(E_pad * 128 * 2);
  __hip_bfloat16* W2s = (__hip_bfloat16*)(w + o); o += al((size_t)128 * 3072 * 2);
  float* featb = (float*)(w + o);                 o += al(E_pad * 48 * 4);
  int* head  = (int*)(w + o);                     o += al((size_t)n_dst * 4);
  int* nxt   = (int*)(w + o);                     o += al((size_t)E * 4);

  hipMemsetAsync(head, 0xFF, (size_t)n_dst * 4, stream);   // head = -1

  const int NW = (128 * WNUMEL) / 256;            // 1536 w2s blocks
  const int NM = (E + 7) / 8;                     // mlp blocks
  const int NP = (E + 255) / 256;                 // prep blocks
  k_pre<<<NW + NM + NP, 256, 0, stream>>>(W2, W2s, edge_scalars, W1, b1, h2s,
                                          edge_vec, dst_idx, shb, head, nxt, E, NW, NM);
  dim3 gg(nblk64, 3);
  k_gemm<<<gg, 256, 0, stream>>>((const u16*)h2s, (const u16*)W2s, h_src, src_idx,
                                 b2, featb, E);
  k_gather<<<(n_dst + 3) / 4, 256, 0, stream>>>(featb, shb, head, nxt,
                                                (float*)d_out, n_dst);
}

// Round 12
// 92.886 us; speedup vs baseline: 1.2357x; 1.2357x over previous
//
#include <hip/hip_runtime.h>
#include <hip/hip_bf16.h>

typedef unsigned short u16;
typedef __attribute__((ext_vector_type(8))) short short8;
typedef __attribute__((ext_vector_type(4))) float f32x4;
typedef __attribute__((ext_vector_type(4))) int i32x4;

#define HID 128
#define WNUMEL 3072
#define OUTD 144

// ---------- fused pre-pass: W2 swizzle | MLP | sh + linked-list build ----------
__global__ void k_pre(const float* __restrict__ W2, __hip_bfloat16* __restrict__ W2s,
                      const float* __restrict__ es, const float* __restrict__ W1,
                      const float* __restrict__ b1, __hip_bfloat16* __restrict__ h2s,
                      const float* __restrict__ ev, const int* __restrict__ dst,
                      float* __restrict__ shb, int* __restrict__ head,
                      int* __restrict__ nxt, int E, int NW, int NM) {
  __shared__ float esl[8][32];
  const int b = blockIdx.x, tid = threadIdx.x;
  if (b < NW) {
    // W2 swizzle, coalesced READ side: f = k*3072+n, scatter-write bf16
    int f = b * 256 + tid;                            // < 128*3072
    int k = f / WNUMEL, n = f - k * WNUMEL;
    int s = k >> 5, h = (k >> 3) & 3, i = k & 7;
    int tt = n >> 4, c = n & 15;
    W2s[((size_t)(tt * 4 + s) * 64 + (c + 16 * h)) * 8 + i] = __float2bfloat16(W2[f]);
  } else if (b < NW + NM) {
    int e0 = (b - NW) * 8;
    {
      int e = e0 + (tid >> 5);
      esl[tid >> 5][tid & 31] = (e < E) ? es[e * 32 + (tid & 31)] : 0.f;
    }
    __syncthreads();
    int h = tid & 127;
    float bh = b1[h];
    // hoist W1 column h: 32 loads once (was 128 L1 re-reads per thread)
    float w1c[32];
#pragma unroll
    for (int i = 0; i < 32; ++i) w1c[i] = W1[i * HID + h];
#pragma unroll
    for (int r = 0; r < 4; ++r) {
      int eloc = (tid >> 7) + r * 2;
      int e = e0 + eloc;
      if (e < E) {
        float acc = bh;
#pragma unroll
        for (int i = 0; i < 32; ++i) acc = fmaf(esl[eloc][i], w1c[i], acc);
        float sg = 1.f / (1.f + expf(-acc));
        float z = acc * sg * 0.125f;                  // fold 1/sqrt(64)
        int s = h >> 5, hh = (h >> 3) & 3, i = h & 7;
        int lane = (e & 15) + 16 * hh, eblk = e >> 4;
        h2s[((size_t)(eblk * 4 + s) * 64 + lane) * 8 + i] = __float2bfloat16(z);
      }
    }
  } else {
    int e = (b - NW - NM) * 256 + tid;
    if (e >= E) return;
    float vx = ev[e * 3 + 0], vy = ev[e * 3 + 1], vz = ev[e * 3 + 2];
    float nrm = fmaxf(sqrtf(vx * vx + vy * vy + vz * vz), 1e-9f);
    float x = vx / nrm, y = vy / nrm, z = vz / nrm;
    const float SQ3 = 1.7320508075688772f, SQ5 = 2.2360679774997896f,
                SQ15 = 3.872983346207417f;
    float* sp = shb + (size_t)e * 9;
    sp[0] = 1.f;
    sp[1] = SQ3 * x; sp[2] = SQ3 * y; sp[3] = SQ3 * z;
    sp[4] = SQ15 * x * y; sp[5] = SQ15 * y * z;
    sp[6] = 0.5f * SQ5 * (3.f * z * z - 1.f);
    sp[7] = SQ15 * x * z;
    sp[8] = 0.5f * SQ15 * (x * x - y * y);
    nxt[e] = atomicExch(&head[dst[e]], e);           // per-dst linked list
  }
}

// ---------- fused GEMM + x-contraction -> feat[E][48] ----------
// EXACT R10 structure; ONLY change: A-fragments XORed with a runtime zero
// (loaded from memory, value unknowable at compile time). The XOR result
// cannot be rematerialized as a load — to recompute it the RA must keep af
// live anyway — so the 16 A-fragments finally stay register-resident instead
// of being re-loaded from L1 at every MFMA use site (the latency chain that
// R6-R11 counters point to). Verdict observable: VGPR_Count 64 -> >=128.
__global__ __launch_bounds__(256, 2) void k_gemm(
    const u16* __restrict__ h2s, const u16* __restrict__ W2s,
    const float* __restrict__ hsrc, const int* __restrict__ srci,
    const float* __restrict__ b2, const int* __restrict__ zbuf,
    float* __restrict__ feat_out, int E) {
  __shared__ float lds[4160];          // xT[64u][64e] (16KB), then fl[4][1040]
  float* xT = lds;
  float* fl = lds;
  const int tid = threadIdx.x, lane = tid & 63, wave = tid >> 6;
  const int blk = blockIdx.x, l3 = blockIdx.y;
  const int c = lane & 15, g = lane >> 4;
  const int z = zbuf[0];               // runtime zero (uniform -> SGPR)
  const i32x4 zv = {z, z, z, z};

  // stage x transposed (wave w stages u-rows [w*16, w*16+16))
  {
    int e = lane, u0 = wave * 16;
    int eg = min(blk * 64 + e, E - 1);
    const float* xr = hsrc + (size_t)srci[eg] * 64 + u0;
#pragma unroll
    for (int k = 0; k < 16; ++k) xT[(u0 + k) * 64 + e] = xr[k];
  }
  // A fragments: loaded once, pinned via opaque XOR-with-runtime-zero
  union AFrag { i32x4 i; short8 s; };
  AFrag af[4][4];
#pragma unroll
  for (int mt = 0; mt < 4; ++mt)
#pragma unroll
    for (int s = 0; s < 4; ++s) {
      af[mt][s].i = *(const i32x4*)(h2s + ((size_t)((blk * 4 + mt) * 4 + s) * 64 + lane) * 8);
      af[mt][s].i ^= zv;
    }
  __syncthreads();

  float feat[4][4] = {};               // [mt][j], this l-path, this wave's u-range
  const int T0 = l3 * 64 + wave * 16;
  const u16* Bg = W2s + (size_t)T0 * 2048;
  const float* b2g = b2 + T0 * 16 + c;

#pragma unroll
  for (int k = 0; k < 16; ++k) {       // wave's 16 N-tiles, no barriers
    short8 bf[4];
#pragma unroll
    for (int s = 0; s < 4; ++s)
      bf[s] = *(const short8*)(Bg + ((size_t)(k * 4 + s) * 64 + lane) * 8);
    float b2v = 0.125f * b2g[k * 16];
#pragma unroll
    for (int mt = 0; mt < 4; ++mt) {
      f32x4 acc = {b2v, b2v, b2v, b2v};
#pragma unroll
      for (int s = 0; s < 4; ++s)
        acc = __builtin_amdgcn_mfma_f32_16x16x32_bf16(af[mt][s].s, bf[s], acc, 0, 0, 0);
      const float4 xv = *(const float4*)&xT[(wave * 16 + k) * 64 + mt * 16 + g * 4];
#pragma unroll
      for (int j = 0; j < 4; ++j)
        feat[mt][j] = fmaf((&xv.x)[j], acc[j], feat[mt][j]);
    }
  }

  // cross-wave feat reduction in LDS (reuses xT space — barrier first)
  __syncthreads();
#pragma unroll
  for (int mt = 0; mt < 4; ++mt)
#pragma unroll
    for (int j = 0; j < 4; ++j)
      fl[wave * 1040 + (mt * 16 + g * 4 + j) * 16 + c] = feat[mt][j];
  __syncthreads();

  // epilogue: sum the 4 wave-partials, store compact feat slice for this l3
#pragma unroll
  for (int r = 0; r < 4; ++r) {
    int p = r * 256 + tid;             // 1024 = 64 edges x 16 v
    int eloc = p >> 4, v = p & 15;
    float f = fl[p] + fl[1040 + p] + fl[2080 + p] + fl[3120 + p];
    int e = blk * 64 + eloc;
    if (e < E) feat_out[(size_t)e * 48 + l3 * 16 + v] = f;
  }
}

// ---------- gather: one wave per dst; walk linked list; apply sh; mean ----------
__global__ void k_gather(const float* __restrict__ feat, const float* __restrict__ shb,
                         const int* __restrict__ head, const int* __restrict__ nxt,
                         float* __restrict__ out, int n_dst) {
  int d = blockIdx.x * 4 + (threadIdx.x >> 6);
  int lane = threadIdx.x & 63;
  if (d >= n_dst) return;
  int fi[4], si[4];
#pragma unroll
  for (int r = 0; r < 4; ++r) {
    int o = lane * 4 + r;
    if (o < 16)      { fi[r] = o;                 si[r] = 0; }        // sh[0] == 1
    else if (o < 64) { int id = o - 16; fi[r] = 16 + id / 3; si[r] = 1 + id % 3; }
    else             { int id = o - 64; fi[r] = 32 + id / 5; si[r] = 4 + id % 5; }
  }
  int e = head[d];                     // same addr across lanes -> broadcast load
  float4 acc = {0.f, 0.f, 0.f, 0.f};
  int deg = 0;
  while (e >= 0) {
    int en = nxt[e];                   // issue next-pointer first (chase overlap)
    if (lane < 36) {
      const float* fp = feat + (size_t)e * 48;
      const float* sp = shb + (size_t)e * 9;
#pragma unroll
      for (int r = 0; r < 4; ++r)
        (&acc.x)[r] = fmaf(fp[fi[r]], sp[si[r]], (&acc.x)[r]);
    }
    ++deg;
    e = en;
  }
  if (lane < 36) {
    float inv = 1.f / (float)max(deg, 1);
    acc.x *= inv; acc.y *= inv; acc.z *= inv; acc.w *= inv;
    *(float4*)&out[(size_t)d * OUTD + lane * 4] = acc;
  }
}

extern "C" void kernel_launch(void* const* d_in, const int* in_sizes, int n_in,
                              void* d_out, int out_size, void* d_ws, size_t ws_size,
                              hipStream_t stream) {
  const float* h_src        = (const float*)d_in[0];
  const float* edge_vec     = (const float*)d_in[1];
  const float* edge_scalars = (const float*)d_in[2];
  const float* W1           = (const float*)d_in[3];
  const float* b1           = (const float*)d_in[4];
  const float* W2           = (const float*)d_in[5];
  const float* b2           = (const float*)d_in[6];
  const int*   src_idx      = (const int*)d_in[7];
  const int*   dst_idx      = (const int*)d_in[8];

  const int E = in_sizes[1] / 3;
  const int n_dst = out_size / OUTD;
  const int nblk64 = (E + 63) / 64;
  const size_t E_pad = (size_t)nblk64 * 64;

  char* w = (char*)d_ws;
  auto al = [](size_t x) { return (x + 255) & ~(size_t)255; };
  size_t o = 0;
  float* shb = (float*)(w + o);                   o += al(E_pad * 9 * 4);
  __hip_bfloat16* h2s = (__hip_bfloat16*)(w + o); o += al(E_pad * 128 * 2);
  __hip_bfloat16* W2s = (__hip_bfloat16*)(w + o); o += al((size_t)128 * 3072 * 2);
  float* featb = (float*)(w + o);                 o += al(E_pad * 48 * 4);
  int* head  = (int*)(w + o);                     o += al((size_t)n_dst * 4);
  int* nxt   = (int*)(w + o);                     o += al((size_t)E * 4);
  int* zbuf  = (int*)(w + o);                     o += al((size_t)256);

  hipMemsetAsync(head, 0xFF, (size_t)n_dst * 4, stream);   // head = -1
  hipMemsetAsync(zbuf, 0, 256, stream);                    // runtime zero for pin

  const int NW = (128 * WNUMEL) / 256;            // 1536 w2s blocks
  const int NM = (E + 7) / 8;                     // mlp blocks
  const int NP = (E + 255) / 256;                 // prep blocks
  k_pre<<<NW + NM + NP, 256, 0, stream>>>(W2, W2s, edge_scalars, W1, b1, h2s,
                                          edge_vec, dst_idx, shb, head, nxt, E, NW, NM);
  dim3 gg(nblk64, 3);
  k_gemm<<<gg, 256, 0, stream>>>((const u16*)h2s, (const u16*)W2s, h_src, src_idx,
                                 b2, zbuf, featb, E);
  k_gather<<<(n_dst + 3) / 4, 256, 0, stream>>>(featb, shb, head, nxt,
                                                (float*)d_out, n_dst);
}